// Round 3
// baseline (377.935 us; speedup 1.0000x reference)
//
#include <hip/hip_runtime.h>
#include <cstdint>
#include <cstddef>

// ---------------------------------------------------------------------------
// SqueezeNet fire module, fully fused:  x --squeeze(1x1,512->64)+ReLU--> S
// (kept in LDS only) --{expand1x1, expand3x3(pad=1)}+ReLU--> out (concat).
// N=32, C_in=512, H=W=56, fp32 in/out.  fp16 MFMA 16x16x32.
// One block = one image x 2 output rows.  Block computes its own 4-row S
// halo tile (squeeze GEMM, coalesced float4 x loads), stores it swizzled in
// LDS, then runs e1 and e3 phases sequentially (acc registers reused).
// S never touches HBM; only launches: tiny weight-prep + this kernel.
// ---------------------------------------------------------------------------

typedef _Float16 f16;
typedef __attribute__((ext_vector_type(8))) _Float16 f16x8;
typedef __attribute__((ext_vector_type(4))) _Float16 f16x4;
typedef __attribute__((ext_vector_type(4))) float    f32x4;

#define MFMA(a, b, c) __builtin_amdgcn_mfma_f32_16x16x32_f16((a), (b), (c), 0, 0, 0)

#define NIMG 32
#define CIN  512
#define HW   3136     // 56*56
#define W56  56
#define CSQ  64
#define CE   256

// swizzled LDS byte offset for S tile position q (0..231), byte col bc (0..127)
__device__ __forceinline__ int sw_off(int q, int bc) {
    return (q * 128 + bc) ^ ((q & 7) << 4);
}

// ---------------------------------------------------------------------------
// prep: fp32 -> fp16 weight conversion + W3 repack to [tap][o][i]
// ---------------------------------------------------------------------------
__global__ __launch_bounds__(256) void fire_prep(
    const float* __restrict__ sw, const float* __restrict__ e1w,
    const float* __restrict__ e3w,
    f16* __restrict__ Wsq, f16* __restrict__ W1, f16* __restrict__ W3)
{
    int t = blockIdx.x * 256 + threadIdx.x;
    if (t < CSQ * CIN) {
        Wsq[t] = (f16)sw[t];
    } else if (t < CSQ * CIN + CE * CSQ) {
        int j = t - CSQ * CIN;
        W1[j] = (f16)e1w[j];
    } else {
        int j = t - (CSQ * CIN + CE * CSQ);
        if (j < 9 * CE * CSQ) {
            int tap = j >> 14;            // 16384 = 256*64 per tap
            int rem = j & 16383;
            int o = rem >> 6;
            int i = rem & 63;
            W3[j] = (f16)e3w[(o * CSQ + i) * 9 + tap];
        }
    }
}

// ---------------------------------------------------------------------------
// fused fire kernel.  grid = (28 row-blocks, 32 images), 256 threads.
// LDS S tile: 4 rows x 58 cols (padded) x 64 ch fp16, XOR-16 swizzled.
// ---------------------------------------------------------------------------
__global__ __launch_bounds__(256) void fire_fused(
    const float* __restrict__ x,  const float* __restrict__ sb,
    const f16* __restrict__ Wsq,  const f16* __restrict__ W1,
    const float* __restrict__ b1, const f16* __restrict__ W3,
    const float* __restrict__ b3, float* __restrict__ out)
{
    __shared__ f16 Slds[4 * 58 * 64];   // 29696 B

    const int tid  = threadIdx.x;
    const int lane = tid & 63, wv = tid >> 6;
    const int i = lane & 15, g = lane >> 4;
    const int n  = blockIdx.y;
    const int rb = blockIdx.x;              // output rows 2rb, 2rb+1
    const int r0 = rb * 2;

    const int vr_start = (r0 == 0) ? 0 : (r0 - 1);        // first valid S row
    const int vr_end   = (r0 + 2 < W56) ? (r0 + 2) : (W56 - 1);
    const int nr       = vr_end - vr_start + 1;           // 3 or 4
    const int nvalid   = nr * W56;                        // 168 or 224 (div by 4)
    const int t_base   = vr_start - (r0 - 1);             // 0 or 1 (pad-top rows)

    // ---- zero the S tile (conv padding + unwritten rows must be 0) ----
    {
        int4* p = (int4*)Slds;
        #pragma unroll
        for (int t = 0; t < 8; ++t) {
            int idx = t * 256 + tid;
            if (idx < 1856) p[idx] = make_int4(0, 0, 0, 0);
        }
    }
    __syncthreads();

    // =================== phase 1: squeeze into LDS =====================
    // wave wv covers px_local [wv*64, wv*64+64) of the valid window.
    // fragment column c (0..3): px_local = wv*64 + 4*i + c  -> one float4
    // global load (16 lanes x 16B = 256B contiguous) feeds all 4 frags.
    {
        const int  pxl0 = wv * 64 + 4 * i;
        const bool ldv  = (pxl0 < nvalid);   // float4 never straddles boundary
        const float* xp = x + (size_t)n * CIN * HW + vr_start * W56 + pxl0;

        if (wv * 64 < nvalid) {
            f32x4 acc[4][4] = {};
            for (int kk = 0; kk < 16; ++kk) {
                const int k0 = kk * 32 + g * 8;
                f16x8 b[4];
                #pragma unroll
                for (int v = 0; v < 8; ++v) {
                    float4 q = make_float4(0.f, 0.f, 0.f, 0.f);
                    if (ldv) q = *(const float4*)(xp + (size_t)(k0 + v) * HW);
                    b[0][v] = (f16)q.x;
                    b[1][v] = (f16)q.y;
                    b[2][v] = (f16)q.z;
                    b[3][v] = (f16)q.w;
                }
                #pragma unroll
                for (int m = 0; m < 4; ++m) {
                    f16x8 a = *(const f16x8*)(Wsq + (16 * m + i) * CIN + k0);
                    #pragma unroll
                    for (int c = 0; c < 4; ++c)
                        acc[m][c] = MFMA(a, b[c], acc[m][c]);
                }
            }
            // store S tile: D row = oc = 16m+4g+v, col = i -> px_local pxl0+c
            if (ldv) {
                #pragma unroll
                for (int m = 0; m < 4; ++m) {
                    const int oc = 16 * m + 4 * g;
                    const float4 bb = *(const float4*)(sb + oc);
                    #pragma unroll
                    for (int c = 0; c < 4; ++c) {
                        const int pxl = pxl0 + c;
                        const int hl  = pxl / W56;          // row in valid window
                        const int col = pxl - hl * W56;
                        const int q   = (t_base + hl) * 58 + col + 1;
                        f16x4 st;
                        st[0] = (f16)fmaxf(acc[m][c][0] + bb.x, 0.f);
                        st[1] = (f16)fmaxf(acc[m][c][1] + bb.y, 0.f);
                        st[2] = (f16)fmaxf(acc[m][c][2] + bb.z, 0.f);
                        st[3] = (f16)fmaxf(acc[m][c][3] + bb.w, 0.f);
                        *(f16x4*)((char*)Slds + sw_off(q, oc * 2)) = st;
                    }
                }
            }
        }
    }
    __syncthreads();

    // per-lane padded-tile position bases for the 7 output-pixel fragments
    int q0[7];
    #pragma unroll
    for (int c = 0; c < 7; ++c) {
        int pl  = 16 * c + i;                 // 0..111 (output px within block)
        int r   = (pl >= W56) ? 1 : 0;
        int col = pl - r * W56;
        q0[c] = r * 58 + col;
    }

    // =================== phase 2: expand1x1 ===========================
    // wave wv owns e1 out-ch 64wv..64wv+63 for the block's 112 px.
    {
        f32x4 acc[4][7] = {};
        #pragma unroll
        for (int kk = 0; kk < 2; ++kk) {
            const int k0 = kk * 32 + g * 8;
            f16x8 b[7];
            #pragma unroll
            for (int c = 0; c < 7; ++c) {
                int q = q0[c] + 59;           // center tap (row+1, col+1)
                b[c] = *(const f16x8*)((const char*)Slds + sw_off(q, kk * 64 + g * 16));
            }
            #pragma unroll
            for (int m = 0; m < 4; ++m) {
                f16x8 a = *(const f16x8*)(W1 + (64 * wv + 16 * m + i) * CSQ + k0);
                #pragma unroll
                for (int c = 0; c < 7; ++c)
                    acc[m][c] = MFMA(a, b[c], acc[m][c]);
            }
        }
        #pragma unroll
        for (int m = 0; m < 4; ++m) {
            const int oc = 64 * wv + 16 * m + 4 * g;
            const float4 bb = *(const float4*)(b1 + oc);
            #pragma unroll
            for (int c = 0; c < 7; ++c) {
                float* op = out + ((size_t)n * 512 + oc) * HW + rb * 112 + 16 * c + i;
                op[0 * (size_t)HW] = fmaxf(acc[m][c][0] + bb.x, 0.f);
                op[1 * (size_t)HW] = fmaxf(acc[m][c][1] + bb.y, 0.f);
                op[2 * (size_t)HW] = fmaxf(acc[m][c][2] + bb.z, 0.f);
                op[3 * (size_t)HW] = fmaxf(acc[m][c][3] + bb.w, 0.f);
            }
        }
    }

    // =================== phase 3: expand3x3 ===========================
    {
        f32x4 acc[4][7] = {};
        for (int dh = 0; dh < 3; ++dh) {
            for (int dw = 0; dw < 3; ++dw) {
                const f16* wtap = W3 + (size_t)(dh * 3 + dw) * CE * CSQ;
                const int toff = dh * 58 + dw;
                #pragma unroll
                for (int kk = 0; kk < 2; ++kk) {
                    const int k0 = kk * 32 + g * 8;
                    f16x8 b[7];
                    #pragma unroll
                    for (int c = 0; c < 7; ++c) {
                        int q = q0[c] + toff;
                        b[c] = *(const f16x8*)((const char*)Slds + sw_off(q, kk * 64 + g * 16));
                    }
                    #pragma unroll
                    for (int m = 0; m < 4; ++m) {
                        f16x8 a = *(const f16x8*)(wtap + (64 * wv + 16 * m + i) * CSQ + k0);
                        #pragma unroll
                        for (int c = 0; c < 7; ++c)
                            acc[m][c] = MFMA(a, b[c], acc[m][c]);
                    }
                }
            }
        }
        #pragma unroll
        for (int m = 0; m < 4; ++m) {
            const int ocl = 64 * wv + 16 * m + 4 * g;
            const float4 bb = *(const float4*)(b3 + ocl);
            #pragma unroll
            for (int c = 0; c < 7; ++c) {
                float* op = out + ((size_t)n * 512 + 256 + ocl) * HW + rb * 112 + 16 * c + i;
                op[0 * (size_t)HW] = fmaxf(acc[m][c][0] + bb.x, 0.f);
                op[1 * (size_t)HW] = fmaxf(acc[m][c][1] + bb.y, 0.f);
                op[2 * (size_t)HW] = fmaxf(acc[m][c][2] + bb.z, 0.f);
                op[3 * (size_t)HW] = fmaxf(acc[m][c][3] + bb.w, 0.f);
            }
        }
    }
}

// ---------------------------------------------------------------------------
extern "C" void kernel_launch(void* const* d_in, const int* in_sizes, int n_in,
                              void* d_out, int out_size, void* d_ws, size_t ws_size,
                              hipStream_t stream)
{
    const float* x  = (const float*)d_in[0];
    const float* sw = (const float*)d_in[1];
    const float* sb = (const float*)d_in[2];
    const float* w1 = (const float*)d_in[3];
    const float* b1 = (const float*)d_in[4];
    const float* w3 = (const float*)d_in[5];
    const float* b3 = (const float*)d_in[6];
    float* out = (float*)d_out;

    // workspace (fp16 weights only): Wsq [64][512], W1 [256][64], W3 [9][256][64]
    f16* Wsq = (f16*)d_ws;
    f16* W1b = Wsq + CSQ * CIN;
    f16* W3b = W1b + CE * CSQ;

    fire_prep<<<768, 256, 0, stream>>>(sw, w1, w3, Wsq, W1b, W3b);
    fire_fused<<<dim3(28, 32), 256, 0, stream>>>(x, sb, Wsq, W1b, b1, W3b, b3, out);
}

// Round 4
// 190.465 us; speedup vs baseline: 1.9843x; 1.9843x over previous
//
#include <hip/hip_runtime.h>
#include <cstdint>
#include <cstddef>

// ---------------------------------------------------------------------------
// SqueezeNet fire module, split pipeline (R4):
//   prep: weights -> fp16 (W3 repacked [tap][o][i])
//   squeeze: x (coalesced float4) -> S fp16 [n][px][64]   (1568 x 1-wave blocks)
//   expand1x1 / expand3x3: MFMA + LDS-transposed epilogue so HBM stores are
//   256-448B contiguous line-aligned runs (R3 showed scattered 64B-segment
//   stores + stalls were the sink, not fetch volume).
// ---------------------------------------------------------------------------

typedef _Float16 f16;
typedef __attribute__((ext_vector_type(8))) _Float16 f16x8;
typedef __attribute__((ext_vector_type(4))) _Float16 f16x4;
typedef __attribute__((ext_vector_type(4))) float    f32x4;

#define MFMA(a, b, c) __builtin_amdgcn_mfma_f32_16x16x32_f16((a), (b), (c), 0, 0, 0)

#define NIMG 32
#define CIN  512
#define HW   3136     // 56*56
#define W56  56
#define CSQ  64
#define CE   256

// ---------------------------------------------------------------------------
// prep: fp32 -> fp16 weight conversion + W3 repack to [tap][o][i]
// ---------------------------------------------------------------------------
__global__ __launch_bounds__(256) void fire_prep(
    const float* __restrict__ sw, const float* __restrict__ e1w,
    const float* __restrict__ e3w,
    f16* __restrict__ Wsq, f16* __restrict__ W1, f16* __restrict__ W3)
{
    int t = blockIdx.x * 256 + threadIdx.x;
    if (t < CSQ * CIN) {
        Wsq[t] = (f16)sw[t];
    } else if (t < CSQ * CIN + CE * CSQ) {
        int j = t - CSQ * CIN;
        W1[j] = (f16)e1w[j];
    } else {
        int j = t - (CSQ * CIN + CE * CSQ);
        if (j < 9 * CE * CSQ) {
            int tap = j >> 14;            // 16384 = 256*64 per tap
            int rem = j & 16383;
            int o = rem >> 6;
            int i = rem & 63;
            W3[j] = (f16)e3w[(o * CSQ + i) * 9 + tap];
        }
    }
}

// ---------------------------------------------------------------------------
// squeeze: S[n][p][64] = relu(Wsq[64x512] @ x + b), fp16 out.
// 1568 blocks x 64 threads (1 wave): wave tile 64 px x 64 oc, coalesced
// float4 x loads (16 lanes x 16B = 256B) feeding 4 interleaved-px B-frags.
// ---------------------------------------------------------------------------
__global__ __launch_bounds__(64) void fire_squeeze3(
    const float* __restrict__ x, const float* __restrict__ sb,
    const f16* __restrict__ Wsq, f16* __restrict__ Sws)
{
    const int lane = threadIdx.x;
    const int i = lane & 15, g = lane >> 4;
    const int w  = blockIdx.x;              // 0..1567
    const int n  = w / 49;
    const int p0 = (w % 49) * 64;

    const float* xp = x + (size_t)n * CIN * HW + p0 + 4 * i;

    f32x4 acc[4][4] = {};
    #pragma unroll
    for (int kk = 0; kk < 16; ++kk) {
        const int k0 = kk * 32 + g * 8;
        f16x8 b[4];
        #pragma unroll
        for (int v = 0; v < 8; ++v) {
            float4 q = *(const float4*)(xp + (size_t)(k0 + v) * HW);
            b[0][v] = (f16)q.x;
            b[1][v] = (f16)q.y;
            b[2][v] = (f16)q.z;
            b[3][v] = (f16)q.w;
        }
        #pragma unroll
        for (int m = 0; m < 4; ++m) {
            f16x8 a = *(const f16x8*)(Wsq + (16 * m + i) * CIN + k0);
            #pragma unroll
            for (int c = 0; c < 4; ++c)
                acc[m][c] = MFMA(a, b[c], acc[m][c]);
        }
    }

    // D: row = oc = 16m + 4g + v, col = i -> pixel p0 + 4i + c
    #pragma unroll
    for (int m = 0; m < 4; ++m) {
        const int oc = 16 * m + 4 * g;
        const float4 bb = *(const float4*)(sb + oc);
        #pragma unroll
        for (int c = 0; c < 4; ++c) {
            const int px = p0 + 4 * i + c;
            f16x4 st;
            st[0] = (f16)fmaxf(acc[m][c][0] + bb.x, 0.f);
            st[1] = (f16)fmaxf(acc[m][c][1] + bb.y, 0.f);
            st[2] = (f16)fmaxf(acc[m][c][2] + bb.z, 0.f);
            st[3] = (f16)fmaxf(acc[m][c][3] + bb.w, 0.f);
            *(f16x4*)(Sws + ((size_t)n * HW + px) * CSQ + oc) = st;
        }
    }
}

// ---------------------------------------------------------------------------
// expand1x1 with LDS-transposed epilogue.  Wave wv: out-ch 64wv..+63,
// px p0..p0+63.  Per m-slice: stage 16ch x 64px f32 in LDS (stride 65,
// conflict-free), read back px-major, store 256B contiguous runs.
// ---------------------------------------------------------------------------
__global__ __launch_bounds__(256) void fire_expand1t(
    const f16* __restrict__ Sws, const f16* __restrict__ W1,
    const float* __restrict__ b1, float* __restrict__ out)
{
    __shared__ float T[4][16 * 65];   // 16.6 KB, per-wave regions

    const int tid  = threadIdx.x;
    const int lane = tid & 63, wv = tid >> 6;
    const int i = lane & 15, g = lane >> 4;
    const int n  = blockIdx.y;
    const int p0 = blockIdx.x * 64;

    f32x4 acc[4][4] = {};
    #pragma unroll
    for (int kk = 0; kk < 2; ++kk) {
        const int k0 = kk * 32 + g * 8;
        f16x8 b[4];
        #pragma unroll
        for (int c = 0; c < 4; ++c)
            b[c] = *(const f16x8*)(Sws + ((size_t)n * HW + p0 + 16 * c + i) * CSQ + k0);
        #pragma unroll
        for (int m = 0; m < 4; ++m) {
            f16x8 a = *(const f16x8*)(W1 + (64 * wv + 16 * m + i) * CSQ + k0);
            #pragma unroll
            for (int c = 0; c < 4; ++c)
                acc[m][c] = MFMA(a, b[c], acc[m][c]);
        }
    }

    float* Tw = T[wv];
    #pragma unroll
    for (int m = 0; m < 4; ++m) {
        const int oc0 = 64 * wv + 16 * m;
        const float4 bb = *(const float4*)(b1 + oc0 + 4 * g);
        const float bbv[4] = {bb.x, bb.y, bb.z, bb.w};
        // stage: T[4g+v][16c+i] = relu(acc + bias)
        #pragma unroll
        for (int c = 0; c < 4; ++c)
            #pragma unroll
            for (int v = 0; v < 4; ++v)
                Tw[(4 * g + v) * 65 + 16 * c + i] = fmaxf(acc[m][c][v] + bbv[v], 0.f);
        // readback px-major, store 64x4B = 256B contiguous per channel row
        #pragma unroll
        for (int r = 0; r < 16; ++r) {
            float val = Tw[r * 65 + lane];
            out[((size_t)n * 512 + oc0 + r) * HW + p0 + lane] = val;
        }
    }
}

// ---------------------------------------------------------------------------
// expand3x3 with LDS-transposed epilogue.  As R2 (implicit GEMM, 9 taps,
// XOR-16 swizzled S tile in LDS) but stores go through per-wave T3 staging:
// 16ch x 112px per m-slice, stride 113, then 256B+192B contiguous runs.
// ---------------------------------------------------------------------------
__global__ __launch_bounds__(256) void fire_expand3t(
    const f16* __restrict__ Sws, const f16* __restrict__ W3,
    const float* __restrict__ b3, float* __restrict__ out)
{
    __shared__ f16   Slds[4 * 58 * 64];   // 29.7 KB
    __shared__ float T3[4][16 * 113];     // 28.9 KB

    const int tid  = threadIdx.x;
    const int lane = tid & 63, wv = tid >> 6;
    const int i = lane & 15, g = lane >> 4;
    const int n  = blockIdx.y;
    const int rb = blockIdx.x;          // 0..27 -> output rows 2rb, 2rb+1
    const int r0 = rb * 2;

    // ---- stage S tile: 232 positions x 8 chunks of 16B ----
    #pragma unroll
    for (int it = 0; it < 8; ++it) {
        int task = it * 256 + tid;
        if (task < 232 * 8) {
            int s  = task >> 3, ck = task & 7;
            int tr = s / 58,   tc = s % 58;
            int h = r0 - 1 + tr, w = tc - 1;
            int4 val = make_int4(0, 0, 0, 0);
            if (h >= 0 && h < W56 && w >= 0 && w < W56)
                val = *(const int4*)(Sws + ((size_t)n * HW + h * W56 + w) * CSQ + ck * 8);
            int off = s * 128 + ck * 16;
            off ^= ((s & 7) << 4);
            *(int4*)((char*)Slds + off) = val;
        }
    }
    __syncthreads();

    int q0[7];
    #pragma unroll
    for (int c = 0; c < 7; ++c) {
        int pl  = 16 * c + i;                 // 0..111
        int r   = (pl >= W56) ? 1 : 0;
        int col = pl - r * W56;
        q0[c] = r * 58 + col;
    }

    f32x4 acc[4][7] = {};
    for (int dh = 0; dh < 3; ++dh) {
        for (int dw = 0; dw < 3; ++dw) {
            const f16* wtap = W3 + (size_t)(dh * 3 + dw) * CE * CSQ;
            const int toff = dh * 58 + dw;
            #pragma unroll
            for (int kk = 0; kk < 2; ++kk) {
                const int k0 = kk * 32 + g * 8;
                f16x8 b[7];
                #pragma unroll
                for (int c = 0; c < 7; ++c) {
                    int q   = q0[c] + toff;
                    int off = (q * 128 + kk * 64 + g * 16) ^ ((q & 7) << 4);
                    b[c] = *(const f16x8*)((const char*)Slds + off);
                }
                #pragma unroll
                for (int m = 0; m < 4; ++m) {
                    f16x8 a = *(const f16x8*)(wtap + (64 * wv + 16 * m + i) * CSQ + k0);
                    #pragma unroll
                    for (int c = 0; c < 7; ++c)
                        acc[m][c] = MFMA(a, b[c], acc[m][c]);
                }
            }
        }
    }

    float* Tw = T3[wv];
    #pragma unroll
    for (int m = 0; m < 4; ++m) {
        const int oc0 = 64 * wv + 16 * m;          // within e3 block
        const float4 bb = *(const float4*)(b3 + oc0 + 4 * g);
        const float bbv[4] = {bb.x, bb.y, bb.z, bb.w};
        #pragma unroll
        for (int c = 0; c < 7; ++c)
            #pragma unroll
            for (int v = 0; v < 4; ++v)
                Tw[(4 * g + v) * 113 + 16 * c + i] = fmaxf(acc[m][c][v] + bbv[v], 0.f);
        #pragma unroll
        for (int r = 0; r < 16; ++r) {
            float* op = out + ((size_t)n * 512 + 256 + oc0 + r) * HW + rb * 112;
            op[lane] = Tw[r * 113 + lane];
            if (lane < 48) op[64 + lane] = Tw[r * 113 + 64 + lane];
        }
    }
}

// ---------------------------------------------------------------------------
extern "C" void kernel_launch(void* const* d_in, const int* in_sizes, int n_in,
                              void* d_out, int out_size, void* d_ws, size_t ws_size,
                              hipStream_t stream)
{
    const float* x  = (const float*)d_in[0];
    const float* sw = (const float*)d_in[1];
    const float* sb = (const float*)d_in[2];
    const float* w1 = (const float*)d_in[3];
    const float* b1 = (const float*)d_in[4];
    const float* w3 = (const float*)d_in[5];
    const float* b3 = (const float*)d_in[6];
    float* out = (float*)d_out;

    // workspace (fp16): S [32][3136][64], Wsq [64][512], W1 [256][64], W3 [9][256][64]
    f16* Sws = (f16*)d_ws;
    f16* Wsq = Sws + (size_t)NIMG * HW * CSQ;
    f16* W1b = Wsq + CSQ * CIN;
    f16* W3b = W1b + CE * CSQ;

    fire_prep<<<768, 256, 0, stream>>>(sw, w1, w3, Wsq, W1b, W3b);
    fire_squeeze3<<<1568, 64, 0, stream>>>(x, sb, Wsq, Sws);
    fire_expand1t<<<dim3(49, 32), 256, 0, stream>>>(Sws, W1b, b1, out);
    fire_expand3t<<<dim3(28, 32), 256, 0, stream>>>(Sws, W3b, b3, out);
}